// Round 3
// baseline (1743.027 us; speedup 1.0000x reference)
//
#include <hip/hip_runtime.h>
#include <hip/hip_fp16.h>

// x = prep(inputs) fused with proc0 -> y;
// per depth: staged single-pass binning into (dst-bucket, src-chunk) cells
// (fixed (cell,block) sub-regions, no global atomics) -> per-(bucket,chunk) reduce
// with XCD-pinned chunk mapping (each XCD's L2 caches one 2MB chunk of y) ->
// packed-fp16 partial acc per chunk -> fused agg(sum partials)+residual+next-proc.

typedef unsigned long long u64;
typedef unsigned int u32;

#define BKT_BITS 10
#define BKT_SIZE 1024
#define MAXNB    512     // buckets (N <= 524288)
#define NBLK     256     // place blocks per depth == reduce blockDim (1:1 sub-lists)

template <int CH> struct Cfg;
template <> struct Cfg<4> { static const int CAPC = 6;  static const int SUBC = 24; };
template <> struct Cfg<2> { static const int CAPC = 14; static const int SUBC = 32; };
template <> struct Cfg<1> { static const int CAPC = 30; static const int SUBC = 64; };

__device__ __forceinline__ float lrelu(float v) { return fmaxf(v, 0.01f * v); }

template <int IN>
__device__ __forceinline__ void mlp3(const float* __restrict__ xin, float* __restrict__ yout,
    const float* __restrict__ sW0, const float* __restrict__ sb0,
    const float* __restrict__ sW1, const float* __restrict__ sb1,
    const float* __restrict__ sW2, const float* __restrict__ sb2)
{
    float h1[16];
#pragma unroll
    for (int o = 0; o < 16; ++o) {
        float s = sb0[o];
#pragma unroll
        for (int a = 0; a < IN; ++a) s = fmaf(xin[a], sW0[a * 16 + o], s);
        h1[o] = lrelu(s);
    }
    float h2[32];
#pragma unroll
    for (int o = 0; o < 32; ++o) {
        float s = sb1[o];
#pragma unroll
        for (int a = 0; a < 16; ++a) s = fmaf(h1[a], sW1[a * 32 + o], s);
        h2[o] = lrelu(s);
    }
#pragma unroll
    for (int o = 0; o < 8; ++o) {
        float s = sb2[o];
#pragma unroll
        for (int a = 0; a < 32; ++a) s = fmaf(h2[a], sW2[a * 8 + o], s);
        yout[o] = lrelu(s);
    }
}

__device__ __forceinline__ void ldw(float* d, const float* s, int n) {
    for (int t = threadIdx.x; t < n; t += 256) d[t] = s[t];
}

__device__ __forceinline__ uint4 pack_h8(const float* y) {
    __half2 p0 = __floats2half2_rn(y[0], y[1]);
    __half2 p1 = __floats2half2_rn(y[2], y[3]);
    __half2 p2 = __floats2half2_rn(y[4], y[5]);
    __half2 p3 = __floats2half2_rn(y[6], y[7]);
    uint4 v;
    v.x = *(u32*)&p0; v.y = *(u32*)&p1; v.z = *(u32*)&p2; v.w = *(u32*)&p3;
    return v;
}

// ---------------- fused prep + proc0: inputs -> x (fp32), y (fp16-packed)
__global__ __launch_bounds__(256) void prep_proc_kernel(
    const float* __restrict__ in, float* __restrict__ x, uint4* __restrict__ y,
    const float* pW0, const float* pb0, const float* pW1, const float* pb1,
    const float* pW2, const float* pb2,
    const float* cW0, const float* cb0, const float* cW1, const float* cb1,
    const float* cW2, const float* cb2, int N)
{
    __shared__ float P0[80],  Pb0[16], P1[512], Pb1[32], P2[256], Pb2[8];
    __shared__ float C0[128], Cb0[16], C1[512], Cb1[32], C2[256], Cb2[8];
    ldw(P0, pW0, 80);  ldw(Pb0, pb0, 16); ldw(P1, pW1, 512); ldw(Pb1, pb1, 32);
    ldw(P2, pW2, 256); ldw(Pb2, pb2, 8);
    ldw(C0, cW0, 128); ldw(Cb0, cb0, 16); ldw(C1, cW1, 512); ldw(Cb1, cb1, 32);
    ldw(C2, cW2, 256); ldw(Cb2, cb2, 8);
    __syncthreads();
    int i = blockIdx.x * 256 + threadIdx.x;
    if (i >= N) return;
    float xin[5];
#pragma unroll
    for (int k = 0; k < 5; ++k) xin[k] = in[(size_t)i * 5 + k];
    float xv[8];
    mlp3<5>(xin, xv, P0, Pb0, P1, Pb1, P2, Pb2);
    float4* xp = (float4*)(x + 8 * (size_t)i);
    xp[0] = make_float4(xv[0], xv[1], xv[2], xv[3]);
    xp[1] = make_float4(xv[4], xv[5], xv[6], xv[7]);
    float yv[8];
    mlp3<8>(xv, yv, C0, Cb0, C1, Cb1, C2, Cb2);
    y[i] = pack_h8(yv);
}

// ---------------- fused agg(sum CHUNKS partials) + masked residual + next proc
template <bool DO_PROC, int CHUNKS>
__global__ __launch_bounds__(256) void aggproc_kernel(
    const uint4* __restrict__ acc, float* __restrict__ x, const float* __restrict__ mask,
    uint4* __restrict__ y,
    const float* aW0, const float* ab0, const float* aW1, const float* ab1,
    const float* aW2, const float* ab2,
    const float* cW0, const float* cb0, const float* cW1, const float* cb1,
    const float* cW2, const float* cb2, int N)
{
    __shared__ float A0[128], Ab0[16], A1[512], Ab1[32], A2[256], Ab2[8];
    __shared__ float C0[128], Cb0[16], C1[512], Cb1[32], C2[256], Cb2[8];
    ldw(A0, aW0, 128); ldw(Ab0, ab0, 16); ldw(A1, aW1, 512); ldw(Ab1, ab1, 32);
    ldw(A2, aW2, 256); ldw(Ab2, ab2, 8);
    if (DO_PROC) {
        ldw(C0, cW0, 128); ldw(Cb0, cb0, 16); ldw(C1, cW1, 512); ldw(Cb1, cb1, 32);
        ldw(C2, cW2, 256); ldw(Cb2, cb2, 8);
    }
    __syncthreads();
    int i = blockIdx.x * 256 + threadIdx.x;
    if (i >= N) return;
    float ain[8] = {0.f, 0.f, 0.f, 0.f, 0.f, 0.f, 0.f, 0.f};
#pragma unroll
    for (int c = 0; c < CHUNKS; ++c) {
        uint4 v = acc[(size_t)c * N + i];
        float2 f0 = __half22float2(*(__half2*)&v.x);
        float2 f1 = __half22float2(*(__half2*)&v.y);
        float2 f2 = __half22float2(*(__half2*)&v.z);
        float2 f3 = __half22float2(*(__half2*)&v.w);
        ain[0] += f0.x; ain[1] += f0.y; ain[2] += f1.x; ain[3] += f1.y;
        ain[4] += f2.x; ain[5] += f2.y; ain[6] += f3.x; ain[7] += f3.y;
    }
    float ya[8];
    mlp3<8>(ain, ya, A0, Ab0, A1, Ab1, A2, Ab2);
    float m = mask[i];
    float4* xp = (float4*)(x + 8 * (size_t)i);
    float4 x0 = xp[0], x1 = xp[1];
    float xn[8] = {x0.x + ya[0] * m, x0.y + ya[1] * m, x0.z + ya[2] * m, x0.w + ya[3] * m,
                   x1.x + ya[4] * m, x1.y + ya[5] * m, x1.z + ya[6] * m, x1.w + ya[7] * m};
    xp[0] = make_float4(xn[0], xn[1], xn[2], xn[3]);
    xp[1] = make_float4(xn[4], xn[5], xn[6], xn[7]);
    if (DO_PROC) {
        float yv[8];
        mlp3<8>(xn, yv, C0, Cb0, C1, Cb1, C2, Cb2);
        y[i] = pack_h8(yv);
    }
}

// ---------------- mask bitmaps for all depths
__global__ __launch_bounds__(256) void mask_pack_kernel(
    const float* __restrict__ masks, u64* __restrict__ bitmaps, int N, int D, int BITW)
{
    int i = blockIdx.x * 256 + threadIdx.x;
    int lane = threadIdx.x & 63;
    for (int d = 0; d < D; ++d) {
        bool b = (i < N) ? (masks[(size_t)d * N + i] != 0.f) : false;
        u64 m = __ballot(b);
        if (lane == 0 && i < N) bitmaps[(size_t)d * BITW + (i >> 6)] = m;
    }
}

// ---------------- single-pass staged binning into (bucket,chunk) cells:
// fixed (cell,block) sub-regions, LDS staging, coalesced drain, no global atomics.
template <int CHUNKS>
__global__ __launch_bounds__(256) void place_kernel(
    const int* __restrict__ src, const int* __restrict__ dst,
    const u64* __restrict__ bitmap,
    u32* __restrict__ ebuf,          // [NB*CHUNKS * NBLK * SUBC]
    int* __restrict__ cnt_g,         // [NB*CHUNKS * NBLK]
    int E, int NB, int shift)
{
    constexpr int CAPC = Cfg<CHUNKS>::CAPC;
    constexpr int SUBC = Cfg<CHUNKS>::SUBC;
    __shared__ int lcnt[MAXNB * CHUNKS];
    __shared__ u32 stage[MAXNB * CHUNKS * CAPC];
    const int cells = NB * CHUNKS;
    for (int t = threadIdx.x; t < cells; t += 256) lcnt[t] = 0;
    __syncthreads();

    const int blk = blockIdx.x;
    const int E4 = E >> 2;
    const int CH4 = (E4 + NBLK - 1) / NBLK;
    const int base4 = blk * CH4;
    const int lim4 = min(base4 + CH4, E4);
    const int4* src4 = (const int4*)src;
    const int4* dst4 = (const int4*)dst;

#define PLACE(dv, sv) { int _d = (dv); \
    if ((bitmap[_d >> 6] >> (_d & 63)) & 1ull) { \
        int _cell = (_d >> BKT_BITS) * CHUNKS + ((u32)(sv) >> shift); \
        int _slot = atomicAdd(&lcnt[_cell], 1); \
        u32 _w = ((u32)(sv) << BKT_BITS) | (u32)(_d & (BKT_SIZE - 1)); \
        if (_slot < CAPC) stage[_cell * CAPC + _slot] = _w; \
        else if (_slot < SUBC) ebuf[((size_t)_cell * NBLK + blk) * SUBC + _slot] = _w; \
    } }

    for (int i4 = base4 + threadIdx.x; i4 < lim4; i4 += 256) {
        int4 dv = dst4[i4];
        int4 sv = src4[i4];
        PLACE(dv.x, sv.x) PLACE(dv.y, sv.y) PLACE(dv.z, sv.z) PLACE(dv.w, sv.w)
    }
    if (blk == NBLK - 1)
        for (int e = (E4 << 2) + threadIdx.x; e < E; e += 256) { PLACE(dst[e], src[e]) }
#undef PLACE

    __syncthreads();
    // drain: pack several cells per wave iteration; contiguous store per cell
    constexpr int SLOTW = (CAPC <= 8) ? 8 : (CAPC <= 16) ? 16 : 32;
    constexpr int CPW = 64 / SLOTW;   // cells per wave per iteration
    int wave = threadIdx.x >> 6, lane = threadIdx.x & 63;
    int cslot = lane % SLOTW, coff = lane / SLOTW;
    for (int c0 = wave * CPW; c0 < cells; c0 += 4 * CPW) {
        int cell = c0 + coff;
        if (cell < cells) {
            int n = lcnt[cell];
            int ns = min(n, CAPC);
            size_t gb = ((size_t)cell * NBLK + blk) * SUBC;
            if (cslot < ns) ebuf[gb + cslot] = stage[cell * CAPC + cslot];
            if (cslot == 0) cnt_g[cell * NBLK + blk] = min(n, SUBC);
        }
    }
}

__device__ __forceinline__ void accum8(float* __restrict__ sacc, u32 w, uint4 v)
{
    int dl = (int)(w & (BKT_SIZE - 1));
    float2 f0 = __half22float2(*(__half2*)&v.x);
    float2 f1 = __half22float2(*(__half2*)&v.y);
    float2 f2 = __half22float2(*(__half2*)&v.z);
    float2 f3 = __half22float2(*(__half2*)&v.w);
    float* a = sacc + dl * 9;
    atomicAdd(a + 0, f0.x); atomicAdd(a + 1, f0.y);
    atomicAdd(a + 2, f1.x); atomicAdd(a + 3, f1.y);
    atomicAdd(a + 4, f2.x); atomicAdd(a + 5, f2.y);
    atomicAdd(a + 6, f3.x); atomicAdd(a + 7, f3.y);
}

// ---------------- per-(bucket,chunk) reduce, thread-per-sub-list, XCD-pinned chunks:
// blockIdx%8 -> XCD (measured round-robin); mapping keeps one src-chunk per XCD so
// each XCD's L2 caches a 2MB slice of y. Writes packed-fp16 partial acc[chunk].
template <int CHUNKS>
__global__ __launch_bounds__(256) void reduce_kernel(
    const uint4* __restrict__ y, const u32* __restrict__ ebuf, const int* __restrict__ cnt_g,
    uint4* __restrict__ acc, int N, int NB)
{
    constexpr int SUBC = Cfg<CHUNKS>::SUBC;
    int i = blockIdx.x, bucket, chunk;
    if (CHUNKS == 4)      { bucket = (i >> 3) * 2 + (i & 1); chunk = (i >> 1) & 3; }
    else if (CHUNKS == 2) { bucket = (i >> 3) * 4 + (i & 3); chunk = (i >> 2) & 1; }
    else                  { bucket = i; chunk = 0; }
    if (bucket >= NB) return;   // uniform across block

    __shared__ float sacc[BKT_SIZE * 9];    // stride 9 spreads banks
    for (int t = threadIdx.x; t < BKT_SIZE * 9; t += 256) sacc[t] = 0.f;
    __syncthreads();

    int cell = bucket * CHUNKS + chunk;
    int sb = cell * NBLK + threadIdx.x;
    int n = cnt_g[sb];
    const u32* r = ebuf + (size_t)sb * SUBC;

    int k = 0;
    for (; k + 3 < n; k += 4) {
        u32 w0 = r[k], w1 = r[k + 1], w2 = r[k + 2], w3 = r[k + 3];
        uint4 v0 = y[w0 >> BKT_BITS];
        uint4 v1 = y[w1 >> BKT_BITS];
        uint4 v2 = y[w2 >> BKT_BITS];
        uint4 v3 = y[w3 >> BKT_BITS];
        accum8(sacc, w0, v0);
        accum8(sacc, w1, v1);
        accum8(sacc, w2, v2);
        accum8(sacc, w3, v3);
    }
    for (; k < n; ++k) {
        u32 w = r[k];
        uint4 v = y[w >> BKT_BITS];
        accum8(sacc, w, v);
    }

    __syncthreads();
    int node0 = bucket << BKT_BITS;
    uint4* accc = acc + (size_t)chunk * N;
    for (int t = threadIdx.x; t < BKT_SIZE; t += 256) {
        int idx = node0 + t;
        if (idx < N) accc[idx] = pack_h8(sacc + t * 9);
    }
}

// ---------------- last-resort fallback: global pk fp16 atomics, mask-skip
__global__ __launch_bounds__(256) void scatter_kernel(
    const uint4* __restrict__ y, const int* __restrict__ src, const int* __restrict__ dst,
    const float* __restrict__ mask, __half2* __restrict__ acc, int E)
{
    int e = blockIdx.x * blockDim.x + threadIdx.x;
    if (e >= E) return;
    int d = dst[e];
    if (mask[d] == 0.f) return;
    int s = src[e];
    uint4 v = y[s];
    __half2* o = acc + 4 * (size_t)d;
    unsafeAtomicAdd(o + 0, *(__half2*)&v.x);
    unsafeAtomicAdd(o + 1, *(__half2*)&v.y);
    unsafeAtomicAdd(o + 2, *(__half2*)&v.z);
    unsafeAtomicAdd(o + 3, *(__half2*)&v.w);
}

template <int CH>
static void run_depth(hipStream_t stream, bool last, int N, int E, int NB, int shift, int nbN,
                      const int* src_d, const int* dst_d, const u64* bitmap_d,
                      u32* ebuf, int* cnt_g, uint4* y, uint4* acc, float* x, const float* mask_d,
                      const float* aW0, const float* ab0, const float* aW1, const float* ab1,
                      const float* aW2, const float* ab2,
                      const float* cW0, const float* cb0, const float* cW1, const float* cb1,
                      const float* cW2, const float* cb2)
{
    place_kernel<CH><<<NBLK, 256, 0, stream>>>(src_d, dst_d, bitmap_d, ebuf, cnt_g, E, NB, shift);
    int rgrid = (CH == 4) ? ((NB + 1) / 2) * 8 : (CH == 2) ? ((NB + 3) / 4) * 8 : NB;
    reduce_kernel<CH><<<rgrid, 256, 0, stream>>>(y, ebuf, cnt_g, acc, N, NB);
    if (!last)
        aggproc_kernel<true, CH><<<nbN, 256, 0, stream>>>(acc, x, mask_d, y,
            aW0, ab0, aW1, ab1, aW2, ab2, cW0, cb0, cW1, cb1, cW2, cb2, N);
    else
        aggproc_kernel<false, CH><<<nbN, 256, 0, stream>>>(acc, x, mask_d, y,
            aW0, ab0, aW1, ab1, aW2, ab2, cW0, cb0, cW1, cb1, cW2, cb2, N);
}

extern "C" void kernel_launch(void* const* d_in, const int* in_sizes, int n_in,
                              void* d_out, int out_size, void* d_ws, size_t ws_size,
                              hipStream_t stream)
{
    const float* inputs  = (const float*)d_in[0];
    const int*   adj_src = (const int*)d_in[1];
    const int*   adj_dst = (const int*)d_in[2];
    const float* masks   = (const float*)d_in[3];

    const float* pW0 = (const float*)d_in[4];  const float* pb0 = (const float*)d_in[5];
    const float* pW1 = (const float*)d_in[6];  const float* pb1 = (const float*)d_in[7];
    const float* pW2 = (const float*)d_in[8];  const float* pb2 = (const float*)d_in[9];
    const float* cW0 = (const float*)d_in[10]; const float* cb0 = (const float*)d_in[11];
    const float* cW1 = (const float*)d_in[12]; const float* cb1 = (const float*)d_in[13];
    const float* cW2 = (const float*)d_in[14]; const float* cb2 = (const float*)d_in[15];
    const float* aW0 = (const float*)d_in[16]; const float* ab0 = (const float*)d_in[17];
    const float* aW1 = (const float*)d_in[18]; const float* ab1 = (const float*)d_in[19];
    const float* aW2 = (const float*)d_in[20]; const float* ab2 = (const float*)d_in[21];

    const int N = in_sizes[0] / 5;
    const int D = in_sizes[3] / N;
    const int E = in_sizes[1] / D;
    const int NB = (N + BKT_SIZE - 1) >> BKT_BITS;
    const int BITW = (N + 63) >> 6;

    float* x = (float*)d_out;

    // pick largest chunk count whose layout fits ws
    auto layout_bytes = [&](int ch) -> size_t {
        int subc = (ch == 4) ? 24 : (ch == 2) ? 32 : 64;
        size_t s = 0;
        auto al = [&](size_t b) { s = (s + b + 255) & ~(size_t)255; };
        al((size_t)N * 16);                          // y
        al((size_t)ch * N * 16);                     // acc partials
        al((size_t)D * BITW * 8);                    // bitmaps
        al((size_t)NB * ch * NBLK * subc * 4);       // ebuf
        al((size_t)NB * ch * NBLK * 4);              // cnt_g
        return s;
    };
    int CHsel = 0;
    if (NB <= MAXNB) {
        if (layout_bytes(4) <= ws_size) CHsel = 4;
        else if (layout_bytes(2) <= ws_size) CHsel = 2;
        else if (layout_bytes(1) <= ws_size) CHsel = 1;
    }
    bool fast = CHsel > 0;
    int subc = (CHsel == 4) ? 24 : (CHsel == 2) ? 32 : 64;

    char* w = (char*)d_ws;
    size_t off = 0;
    auto take = [&](size_t bytes) { char* p = w + off; off = (off + bytes + 255) & ~(size_t)255; return p; };
    uint4* y   = (uint4*)take((size_t)N * 16);
    uint4* acc = (uint4*)take((size_t)(fast ? CHsel : 1) * N * 16);
    u64* bitmaps = (u64*)take((size_t)D * BITW * 8);
    u32* ebuf  = fast ? (u32*)take((size_t)NB * CHsel * NBLK * subc * 4) : nullptr;
    int* cnt_g = fast ? (int*)take((size_t)NB * CHsel * NBLK * 4) : nullptr;

    int shift = 0;
    if (fast) { while ((u32)(N - 1) >> shift >= (u32)CHsel) shift++; }

    const int BLK = 256;
    const int nbN = (N + BLK - 1) / BLK;
    const int nbE = (E + BLK - 1) / BLK;

    if (fast)
        mask_pack_kernel<<<nbN, BLK, 0, stream>>>(masks, bitmaps, N, D, BITW);

    // prep + proc0 -> x, y
    prep_proc_kernel<<<nbN, BLK, 0, stream>>>(inputs, x, y,
                                              pW0, pb0, pW1, pb1, pW2, pb2,
                                              cW0, cb0, cW1, cb1, cW2, cb2, N);

    for (int d = 0; d < D; ++d) {
        const float* mask_d = masks + (size_t)d * N;
        const int* src_d = adj_src + (size_t)d * E;
        const int* dst_d = adj_dst + (size_t)d * E;
        bool last = (d == D - 1);

        if (fast) {
            const u64* bm = bitmaps + (size_t)d * BITW;
            if (CHsel == 4)
                run_depth<4>(stream, last, N, E, NB, shift, nbN, src_d, dst_d, bm, ebuf, cnt_g,
                             y, acc, x, mask_d, aW0, ab0, aW1, ab1, aW2, ab2,
                             cW0, cb0, cW1, cb1, cW2, cb2);
            else if (CHsel == 2)
                run_depth<2>(stream, last, N, E, NB, shift, nbN, src_d, dst_d, bm, ebuf, cnt_g,
                             y, acc, x, mask_d, aW0, ab0, aW1, ab1, aW2, ab2,
                             cW0, cb0, cW1, cb1, cW2, cb2);
            else
                run_depth<1>(stream, last, N, E, NB, shift, nbN, src_d, dst_d, bm, ebuf, cnt_g,
                             y, acc, x, mask_d, aW0, ab0, aW1, ab1, aW2, ab2,
                             cW0, cb0, cW1, cb1, cW2, cb2);
        } else {
            hipMemsetAsync(acc, 0, (size_t)N * 16, stream);
            scatter_kernel<<<nbE, BLK, 0, stream>>>(y, src_d, dst_d, mask_d, (__half2*)acc, E);
            if (!last)
                aggproc_kernel<true, 1><<<nbN, BLK, 0, stream>>>(acc, x, mask_d, y,
                    aW0, ab0, aW1, ab1, aW2, ab2, cW0, cb0, cW1, cb1, cW2, cb2, N);
            else
                aggproc_kernel<false, 1><<<nbN, BLK, 0, stream>>>(acc, x, mask_d, y,
                    aW0, ab0, aW1, ab1, aW2, ab2, cW0, cb0, cW1, cb1, cW2, cb2, N);
        }
    }
}

// Round 4
// 1373.314 us; speedup vs baseline: 1.2692x; 1.2692x over previous
//
#include <hip/hip_runtime.h>
#include <hip/hip_fp16.h>

// x = prep(inputs) fused with proc0 -> y;
// per depth: staged single-pass binning into (dst-bucket, src-chunk) cells
// (fixed (cell,block) sub-regions, no global atomics) -> per-(bucket,chunk) reduce
// with XCD-pinned chunk mapping (each XCD's L2 caches one 2MB chunk of y) and
// packed-fp16 LDS atomics (ds_pk_add_f16: 4 atomics/entry, no h2f converts) ->
// packed-fp16 partial acc per chunk -> fused agg(sum partials)+residual+next-proc.

typedef unsigned long long u64;
typedef unsigned int u32;

#define BKT_BITS 10
#define BKT_SIZE 1024
#define MAXNB    512     // buckets (N <= 524288)
#define NBLK     256     // place blocks per depth == reduce blockDim (1:1 sub-lists)

template <int CH> struct Cfg;
template <> struct Cfg<4> { static const int CAPC = 6;  static const int SUBC = 24; };
template <> struct Cfg<2> { static const int CAPC = 14; static const int SUBC = 32; };
template <> struct Cfg<1> { static const int CAPC = 30; static const int SUBC = 64; };

__device__ __forceinline__ float lrelu(float v) { return fmaxf(v, 0.01f * v); }

template <int IN>
__device__ __forceinline__ void mlp3(const float* __restrict__ xin, float* __restrict__ yout,
    const float* __restrict__ sW0, const float* __restrict__ sb0,
    const float* __restrict__ sW1, const float* __restrict__ sb1,
    const float* __restrict__ sW2, const float* __restrict__ sb2)
{
    float h1[16];
#pragma unroll
    for (int o = 0; o < 16; ++o) {
        float s = sb0[o];
#pragma unroll
        for (int a = 0; a < IN; ++a) s = fmaf(xin[a], sW0[a * 16 + o], s);
        h1[o] = lrelu(s);
    }
    float h2[32];
#pragma unroll
    for (int o = 0; o < 32; ++o) {
        float s = sb1[o];
#pragma unroll
        for (int a = 0; a < 16; ++a) s = fmaf(h1[a], sW1[a * 32 + o], s);
        h2[o] = lrelu(s);
    }
#pragma unroll
    for (int o = 0; o < 8; ++o) {
        float s = sb2[o];
#pragma unroll
        for (int a = 0; a < 32; ++a) s = fmaf(h2[a], sW2[a * 8 + o], s);
        yout[o] = lrelu(s);
    }
}

__device__ __forceinline__ void ldw(float* d, const float* s, int n) {
    for (int t = threadIdx.x; t < n; t += 256) d[t] = s[t];
}

__device__ __forceinline__ uint4 pack_h8(const float* y) {
    __half2 p0 = __floats2half2_rn(y[0], y[1]);
    __half2 p1 = __floats2half2_rn(y[2], y[3]);
    __half2 p2 = __floats2half2_rn(y[4], y[5]);
    __half2 p3 = __floats2half2_rn(y[6], y[7]);
    uint4 v;
    v.x = *(u32*)&p0; v.y = *(u32*)&p1; v.z = *(u32*)&p2; v.w = *(u32*)&p3;
    return v;
}

// ---------------- fused prep + proc0: inputs -> x (fp32), y (fp16-packed)
__global__ __launch_bounds__(256) void prep_proc_kernel(
    const float* __restrict__ in, float* __restrict__ x, uint4* __restrict__ y,
    const float* pW0, const float* pb0, const float* pW1, const float* pb1,
    const float* pW2, const float* pb2,
    const float* cW0, const float* cb0, const float* cW1, const float* cb1,
    const float* cW2, const float* cb2, int N)
{
    __shared__ float P0[80],  Pb0[16], P1[512], Pb1[32], P2[256], Pb2[8];
    __shared__ float C0[128], Cb0[16], C1[512], Cb1[32], C2[256], Cb2[8];
    ldw(P0, pW0, 80);  ldw(Pb0, pb0, 16); ldw(P1, pW1, 512); ldw(Pb1, pb1, 32);
    ldw(P2, pW2, 256); ldw(Pb2, pb2, 8);
    ldw(C0, cW0, 128); ldw(Cb0, cb0, 16); ldw(C1, cW1, 512); ldw(Cb1, cb1, 32);
    ldw(C2, cW2, 256); ldw(Cb2, cb2, 8);
    __syncthreads();
    int i = blockIdx.x * 256 + threadIdx.x;
    if (i >= N) return;
    float xin[5];
#pragma unroll
    for (int k = 0; k < 5; ++k) xin[k] = in[(size_t)i * 5 + k];
    float xv[8];
    mlp3<5>(xin, xv, P0, Pb0, P1, Pb1, P2, Pb2);
    float4* xp = (float4*)(x + 8 * (size_t)i);
    xp[0] = make_float4(xv[0], xv[1], xv[2], xv[3]);
    xp[1] = make_float4(xv[4], xv[5], xv[6], xv[7]);
    float yv[8];
    mlp3<8>(xv, yv, C0, Cb0, C1, Cb1, C2, Cb2);
    y[i] = pack_h8(yv);
}

// ---------------- fused agg(sum CHUNKS partials) + masked residual + next proc
template <bool DO_PROC, int CHUNKS>
__global__ __launch_bounds__(256) void aggproc_kernel(
    const uint4* __restrict__ acc, float* __restrict__ x, const float* __restrict__ mask,
    uint4* __restrict__ y,
    const float* aW0, const float* ab0, const float* aW1, const float* ab1,
    const float* aW2, const float* ab2,
    const float* cW0, const float* cb0, const float* cW1, const float* cb1,
    const float* cW2, const float* cb2, int N)
{
    __shared__ float A0[128], Ab0[16], A1[512], Ab1[32], A2[256], Ab2[8];
    __shared__ float C0[128], Cb0[16], C1[512], Cb1[32], C2[256], Cb2[8];
    ldw(A0, aW0, 128); ldw(Ab0, ab0, 16); ldw(A1, aW1, 512); ldw(Ab1, ab1, 32);
    ldw(A2, aW2, 256); ldw(Ab2, ab2, 8);
    if (DO_PROC) {
        ldw(C0, cW0, 128); ldw(Cb0, cb0, 16); ldw(C1, cW1, 512); ldw(Cb1, cb1, 32);
        ldw(C2, cW2, 256); ldw(Cb2, cb2, 8);
    }
    __syncthreads();
    int i = blockIdx.x * 256 + threadIdx.x;
    if (i >= N) return;
    float ain[8] = {0.f, 0.f, 0.f, 0.f, 0.f, 0.f, 0.f, 0.f};
#pragma unroll
    for (int c = 0; c < CHUNKS; ++c) {
        uint4 v = acc[(size_t)c * N + i];
        float2 f0 = __half22float2(*(__half2*)&v.x);
        float2 f1 = __half22float2(*(__half2*)&v.y);
        float2 f2 = __half22float2(*(__half2*)&v.z);
        float2 f3 = __half22float2(*(__half2*)&v.w);
        ain[0] += f0.x; ain[1] += f0.y; ain[2] += f1.x; ain[3] += f1.y;
        ain[4] += f2.x; ain[5] += f2.y; ain[6] += f3.x; ain[7] += f3.y;
    }
    float ya[8];
    mlp3<8>(ain, ya, A0, Ab0, A1, Ab1, A2, Ab2);
    float m = mask[i];
    float4* xp = (float4*)(x + 8 * (size_t)i);
    float4 x0 = xp[0], x1 = xp[1];
    float xn[8] = {x0.x + ya[0] * m, x0.y + ya[1] * m, x0.z + ya[2] * m, x0.w + ya[3] * m,
                   x1.x + ya[4] * m, x1.y + ya[5] * m, x1.z + ya[6] * m, x1.w + ya[7] * m};
    xp[0] = make_float4(xn[0], xn[1], xn[2], xn[3]);
    xp[1] = make_float4(xn[4], xn[5], xn[6], xn[7]);
    if (DO_PROC) {
        float yv[8];
        mlp3<8>(xn, yv, C0, Cb0, C1, Cb1, C2, Cb2);
        y[i] = pack_h8(yv);
    }
}

// ---------------- mask bitmaps for all depths
__global__ __launch_bounds__(256) void mask_pack_kernel(
    const float* __restrict__ masks, u64* __restrict__ bitmaps, int N, int D, int BITW)
{
    int i = blockIdx.x * 256 + threadIdx.x;
    int lane = threadIdx.x & 63;
    for (int d = 0; d < D; ++d) {
        bool b = (i < N) ? (masks[(size_t)d * N + i] != 0.f) : false;
        u64 m = __ballot(b);
        if (lane == 0 && i < N) bitmaps[(size_t)d * BITW + (i >> 6)] = m;
    }
}

// ---------------- single-pass staged binning into (bucket,chunk) cells:
// fixed (cell,block) sub-regions, LDS staging, coalesced drain, no global atomics.
template <int CHUNKS>
__global__ __launch_bounds__(256) void place_kernel(
    const int* __restrict__ src, const int* __restrict__ dst,
    const u64* __restrict__ bitmap,
    u32* __restrict__ ebuf,          // [NB*CHUNKS * NBLK * SUBC]
    int* __restrict__ cnt_g,         // [NB*CHUNKS * NBLK]
    int E, int NB, int shift)
{
    constexpr int CAPC = Cfg<CHUNKS>::CAPC;
    constexpr int SUBC = Cfg<CHUNKS>::SUBC;
    __shared__ int lcnt[MAXNB * CHUNKS];
    __shared__ u32 stage[MAXNB * CHUNKS * CAPC];
    const int cells = NB * CHUNKS;
    for (int t = threadIdx.x; t < cells; t += 256) lcnt[t] = 0;
    __syncthreads();

    const int blk = blockIdx.x;
    const int E4 = E >> 2;
    const int CH4 = (E4 + NBLK - 1) / NBLK;
    const int base4 = blk * CH4;
    const int lim4 = min(base4 + CH4, E4);
    const int4* src4 = (const int4*)src;
    const int4* dst4 = (const int4*)dst;

#define PLACE(dv, sv) { int _d = (dv); \
    if ((bitmap[_d >> 6] >> (_d & 63)) & 1ull) { \
        int _cell = (_d >> BKT_BITS) * CHUNKS + ((u32)(sv) >> shift); \
        int _slot = atomicAdd(&lcnt[_cell], 1); \
        u32 _w = ((u32)(sv) << BKT_BITS) | (u32)(_d & (BKT_SIZE - 1)); \
        if (_slot < CAPC) stage[_cell * CAPC + _slot] = _w; \
        else if (_slot < SUBC) ebuf[((size_t)_cell * NBLK + blk) * SUBC + _slot] = _w; \
    } }

    for (int i4 = base4 + threadIdx.x; i4 < lim4; i4 += 256) {
        int4 dv = dst4[i4];
        int4 sv = src4[i4];
        PLACE(dv.x, sv.x) PLACE(dv.y, sv.y) PLACE(dv.z, sv.z) PLACE(dv.w, sv.w)
    }
    if (blk == NBLK - 1)
        for (int e = (E4 << 2) + threadIdx.x; e < E; e += 256) { PLACE(dst[e], src[e]) }
#undef PLACE

    __syncthreads();
    // drain: pack several cells per wave iteration; contiguous store per cell
    constexpr int SLOTW = (CAPC <= 8) ? 8 : (CAPC <= 16) ? 16 : 32;
    constexpr int CPW = 64 / SLOTW;   // cells per wave per iteration
    int wave = threadIdx.x >> 6, lane = threadIdx.x & 63;
    int cslot = lane % SLOTW, coff = lane / SLOTW;
    for (int c0 = wave * CPW; c0 < cells; c0 += 4 * CPW) {
        int cell = c0 + coff;
        if (cell < cells) {
            int n = lcnt[cell];
            int ns = min(n, CAPC);
            size_t gb = ((size_t)cell * NBLK + blk) * SUBC;
            if (cslot < ns) ebuf[gb + cslot] = stage[cell * CAPC + cslot];
            if (cslot == 0) cnt_g[cell * NBLK + blk] = min(n, SUBC);
        }
    }
}

// packed-fp16 LDS accumulate: 4 ds_pk_add_f16 per entry, no converts.
// sacc layout: node dl -> 4 half2 slots at stride 5 (bank spread).
__device__ __forceinline__ void accum4(__half2* __restrict__ sacc, u32 w, uint4 v)
{
    int dl = (int)(w & (BKT_SIZE - 1));
    __half2* a = sacc + dl * 5;
    unsafeAtomicAdd(a + 0, *(__half2*)&v.x);
    unsafeAtomicAdd(a + 1, *(__half2*)&v.y);
    unsafeAtomicAdd(a + 2, *(__half2*)&v.z);
    unsafeAtomicAdd(a + 3, *(__half2*)&v.w);
}

// ---------------- per-(bucket,chunk) reduce, thread-per-sub-list, XCD-pinned chunks:
// blockIdx%8 -> XCD (measured round-robin); mapping keeps one src-chunk per XCD so
// each XCD's L2 caches a 2MB slice of y. Writes packed-fp16 partial acc[chunk].
template <int CHUNKS>
__global__ __launch_bounds__(256) void reduce_kernel(
    const uint4* __restrict__ y, const u32* __restrict__ ebuf, const int* __restrict__ cnt_g,
    uint4* __restrict__ acc, int N, int NB)
{
    constexpr int SUBC = Cfg<CHUNKS>::SUBC;
    int i = blockIdx.x, bucket, chunk;
    if (CHUNKS == 4)      { bucket = (i >> 3) * 2 + (i & 1); chunk = (i >> 1) & 3; }
    else if (CHUNKS == 2) { bucket = (i >> 3) * 4 + (i & 3); chunk = (i >> 2) & 1; }
    else                  { bucket = i; chunk = 0; }
    if (bucket >= NB) return;   // uniform across block

    __shared__ __half2 sacc[BKT_SIZE * 5];   // 20 KB; stride 5 spreads banks
    for (int t = threadIdx.x; t < BKT_SIZE * 5; t += 256) ((u32*)sacc)[t] = 0u;
    __syncthreads();

    int cell = bucket * CHUNKS + chunk;
    int sb = cell * NBLK + threadIdx.x;
    int n = cnt_g[sb];
    const u32* r = ebuf + (size_t)sb * SUBC;

    int k = 0;
    for (; k + 3 < n; k += 4) {
        u32 w0 = r[k], w1 = r[k + 1], w2 = r[k + 2], w3 = r[k + 3];
        uint4 v0 = y[w0 >> BKT_BITS];
        uint4 v1 = y[w1 >> BKT_BITS];
        uint4 v2 = y[w2 >> BKT_BITS];
        uint4 v3 = y[w3 >> BKT_BITS];
        accum4(sacc, w0, v0);
        accum4(sacc, w1, v1);
        accum4(sacc, w2, v2);
        accum4(sacc, w3, v3);
    }
    for (; k < n; ++k) {
        u32 w = r[k];
        uint4 v = y[w >> BKT_BITS];
        accum4(sacc, w, v);
    }

    __syncthreads();
    int node0 = bucket << BKT_BITS;
    uint4* accc = acc + (size_t)chunk * N;
    for (int t = threadIdx.x; t < BKT_SIZE; t += 256) {
        int idx = node0 + t;
        if (idx < N) {
            __half2* a = sacc + t * 5;
            uint4 o;
            o.x = *(u32*)(a + 0); o.y = *(u32*)(a + 1);
            o.z = *(u32*)(a + 2); o.w = *(u32*)(a + 3);
            accc[idx] = o;
        }
    }
}

// ---------------- last-resort fallback: global pk fp16 atomics, mask-skip
__global__ __launch_bounds__(256) void scatter_kernel(
    const uint4* __restrict__ y, const int* __restrict__ src, const int* __restrict__ dst,
    const float* __restrict__ mask, __half2* __restrict__ acc, int E)
{
    int e = blockIdx.x * blockDim.x + threadIdx.x;
    if (e >= E) return;
    int d = dst[e];
    if (mask[d] == 0.f) return;
    int s = src[e];
    uint4 v = y[s];
    __half2* o = acc + 4 * (size_t)d;
    unsafeAtomicAdd(o + 0, *(__half2*)&v.x);
    unsafeAtomicAdd(o + 1, *(__half2*)&v.y);
    unsafeAtomicAdd(o + 2, *(__half2*)&v.z);
    unsafeAtomicAdd(o + 3, *(__half2*)&v.w);
}

template <int CH>
static void run_depth(hipStream_t stream, bool last, int N, int E, int NB, int shift, int nbN,
                      const int* src_d, const int* dst_d, const u64* bitmap_d,
                      u32* ebuf, int* cnt_g, uint4* y, uint4* acc, float* x, const float* mask_d,
                      const float* aW0, const float* ab0, const float* aW1, const float* ab1,
                      const float* aW2, const float* ab2,
                      const float* cW0, const float* cb0, const float* cW1, const float* cb1,
                      const float* cW2, const float* cb2)
{
    place_kernel<CH><<<NBLK, 256, 0, stream>>>(src_d, dst_d, bitmap_d, ebuf, cnt_g, E, NB, shift);
    int rgrid = (CH == 4) ? ((NB + 1) / 2) * 8 : (CH == 2) ? ((NB + 3) / 4) * 8 : NB;
    reduce_kernel<CH><<<rgrid, 256, 0, stream>>>(y, ebuf, cnt_g, acc, N, NB);
    if (!last)
        aggproc_kernel<true, CH><<<nbN, 256, 0, stream>>>(acc, x, mask_d, y,
            aW0, ab0, aW1, ab1, aW2, ab2, cW0, cb0, cW1, cb1, cW2, cb2, N);
    else
        aggproc_kernel<false, CH><<<nbN, 256, 0, stream>>>(acc, x, mask_d, y,
            aW0, ab0, aW1, ab1, aW2, ab2, cW0, cb0, cW1, cb1, cW2, cb2, N);
}

extern "C" void kernel_launch(void* const* d_in, const int* in_sizes, int n_in,
                              void* d_out, int out_size, void* d_ws, size_t ws_size,
                              hipStream_t stream)
{
    const float* inputs  = (const float*)d_in[0];
    const int*   adj_src = (const int*)d_in[1];
    const int*   adj_dst = (const int*)d_in[2];
    const float* masks   = (const float*)d_in[3];

    const float* pW0 = (const float*)d_in[4];  const float* pb0 = (const float*)d_in[5];
    const float* pW1 = (const float*)d_in[6];  const float* pb1 = (const float*)d_in[7];
    const float* pW2 = (const float*)d_in[8];  const float* pb2 = (const float*)d_in[9];
    const float* cW0 = (const float*)d_in[10]; const float* cb0 = (const float*)d_in[11];
    const float* cW1 = (const float*)d_in[12]; const float* cb1 = (const float*)d_in[13];
    const float* cW2 = (const float*)d_in[14]; const float* cb2 = (const float*)d_in[15];
    const float* aW0 = (const float*)d_in[16]; const float* ab0 = (const float*)d_in[17];
    const float* aW1 = (const float*)d_in[18]; const float* ab1 = (const float*)d_in[19];
    const float* aW2 = (const float*)d_in[20]; const float* ab2 = (const float*)d_in[21];

    const int N = in_sizes[0] / 5;
    const int D = in_sizes[3] / N;
    const int E = in_sizes[1] / D;
    const int NB = (N + BKT_SIZE - 1) >> BKT_BITS;
    const int BITW = (N + 63) >> 6;

    float* x = (float*)d_out;

    // pick largest chunk count whose layout fits ws
    auto layout_bytes = [&](int ch) -> size_t {
        int subc = (ch == 4) ? 24 : (ch == 2) ? 32 : 64;
        size_t s = 0;
        auto al = [&](size_t b) { s = (s + b + 255) & ~(size_t)255; };
        al((size_t)N * 16);                          // y
        al((size_t)ch * N * 16);                     // acc partials
        al((size_t)D * BITW * 8);                    // bitmaps
        al((size_t)NB * ch * NBLK * subc * 4);       // ebuf
        al((size_t)NB * ch * NBLK * 4);              // cnt_g
        return s;
    };
    int CHsel = 0;
    if (NB <= MAXNB) {
        if (layout_bytes(4) <= ws_size) CHsel = 4;
        else if (layout_bytes(2) <= ws_size) CHsel = 2;
        else if (layout_bytes(1) <= ws_size) CHsel = 1;
    }
    bool fast = CHsel > 0;
    int subc = (CHsel == 4) ? 24 : (CHsel == 2) ? 32 : 64;

    char* w = (char*)d_ws;
    size_t off = 0;
    auto take = [&](size_t bytes) { char* p = w + off; off = (off + bytes + 255) & ~(size_t)255; return p; };
    uint4* y   = (uint4*)take((size_t)N * 16);
    uint4* acc = (uint4*)take((size_t)(fast ? CHsel : 1) * N * 16);
    u64* bitmaps = (u64*)take((size_t)D * BITW * 8);
    u32* ebuf  = fast ? (u32*)take((size_t)NB * CHsel * NBLK * subc * 4) : nullptr;
    int* cnt_g = fast ? (int*)take((size_t)NB * CHsel * NBLK * 4) : nullptr;

    int shift = 0;
    if (fast) { while ((u32)(N - 1) >> shift >= (u32)CHsel) shift++; }

    const int BLK = 256;
    const int nbN = (N + BLK - 1) / BLK;
    const int nbE = (E + BLK - 1) / BLK;

    if (fast)
        mask_pack_kernel<<<nbN, BLK, 0, stream>>>(masks, bitmaps, N, D, BITW);

    // prep + proc0 -> x, y
    prep_proc_kernel<<<nbN, BLK, 0, stream>>>(inputs, x, y,
                                              pW0, pb0, pW1, pb1, pW2, pb2,
                                              cW0, cb0, cW1, cb1, cW2, cb2, N);

    for (int d = 0; d < D; ++d) {
        const float* mask_d = masks + (size_t)d * N;
        const int* src_d = adj_src + (size_t)d * E;
        const int* dst_d = adj_dst + (size_t)d * E;
        bool last = (d == D - 1);

        if (fast) {
            const u64* bm = bitmaps + (size_t)d * BITW;
            if (CHsel == 4)
                run_depth<4>(stream, last, N, E, NB, shift, nbN, src_d, dst_d, bm, ebuf, cnt_g,
                             y, acc, x, mask_d, aW0, ab0, aW1, ab1, aW2, ab2,
                             cW0, cb0, cW1, cb1, cW2, cb2);
            else if (CHsel == 2)
                run_depth<2>(stream, last, N, E, NB, shift, nbN, src_d, dst_d, bm, ebuf, cnt_g,
                             y, acc, x, mask_d, aW0, ab0, aW1, ab1, aW2, ab2,
                             cW0, cb0, cW1, cb1, cW2, cb2);
            else
                run_depth<1>(stream, last, N, E, NB, shift, nbN, src_d, dst_d, bm, ebuf, cnt_g,
                             y, acc, x, mask_d, aW0, ab0, aW1, ab1, aW2, ab2,
                             cW0, cb0, cW1, cb1, cW2, cb2);
        } else {
            hipMemsetAsync(acc, 0, (size_t)N * 16, stream);
            scatter_kernel<<<nbE, BLK, 0, stream>>>(y, src_d, dst_d, mask_d, (__half2*)acc, E);
            if (!last)
                aggproc_kernel<true, 1><<<nbN, BLK, 0, stream>>>(acc, x, mask_d, y,
                    aW0, ab0, aW1, ab1, aW2, ab2, cW0, cb0, cW1, cb1, cW2, cb2, N);
            else
                aggproc_kernel<false, 1><<<nbN, BLK, 0, stream>>>(acc, x, mask_d, y,
                    aW0, ab0, aW1, ab1, aW2, ab2, cW0, cb0, cW1, cb1, cW2, cb2, N);
        }
    }
}

// Round 5
// 1345.365 us; speedup vs baseline: 1.2956x; 1.0208x over previous
//
#include <hip/hip_runtime.h>
#include <hip/hip_fp16.h>

// x = prep(inputs) fused with proc0 -> y;
// ALL depths' binning batched into one place launch (2 blocks/CU vs 1: place is
// occupancy-starved, not bandwidth-bound) -> per depth: per-(bucket,chunk) reduce
// with XCD-pinned chunk mapping (each XCD's L2 caches one 2MB chunk of y) and
// packed-fp16 LDS atomics -> packed-fp16 partial acc per chunk ->
// fused agg(sum partials)+residual+next-proc.

typedef unsigned long long u64;
typedef unsigned int u32;

#define BKT_BITS 10
#define BKT_SIZE 1024
#define MAXNB    512     // buckets (N <= 524288)
#define NBLK     256     // place blocks per depth == reduce blockDim (1:1 sub-lists)

template <int CH> struct Cfg;
template <> struct Cfg<4> { static const int CAPC = 6;  static const int SUBC = 24; };
template <> struct Cfg<2> { static const int CAPC = 14; static const int SUBC = 32; };
template <> struct Cfg<1> { static const int CAPC = 30; static const int SUBC = 64; };

__device__ __forceinline__ float lrelu(float v) { return fmaxf(v, 0.01f * v); }

template <int IN>
__device__ __forceinline__ void mlp3(const float* __restrict__ xin, float* __restrict__ yout,
    const float* __restrict__ sW0, const float* __restrict__ sb0,
    const float* __restrict__ sW1, const float* __restrict__ sb1,
    const float* __restrict__ sW2, const float* __restrict__ sb2)
{
    float h1[16];
#pragma unroll
    for (int o = 0; o < 16; ++o) {
        float s = sb0[o];
#pragma unroll
        for (int a = 0; a < IN; ++a) s = fmaf(xin[a], sW0[a * 16 + o], s);
        h1[o] = lrelu(s);
    }
    float h2[32];
#pragma unroll
    for (int o = 0; o < 32; ++o) {
        float s = sb1[o];
#pragma unroll
        for (int a = 0; a < 16; ++a) s = fmaf(h1[a], sW1[a * 32 + o], s);
        h2[o] = lrelu(s);
    }
#pragma unroll
    for (int o = 0; o < 8; ++o) {
        float s = sb2[o];
#pragma unroll
        for (int a = 0; a < 32; ++a) s = fmaf(h2[a], sW2[a * 8 + o], s);
        yout[o] = lrelu(s);
    }
}

__device__ __forceinline__ void ldw(float* d, const float* s, int n) {
    for (int t = threadIdx.x; t < n; t += 256) d[t] = s[t];
}

__device__ __forceinline__ uint4 pack_h8(const float* y) {
    __half2 p0 = __floats2half2_rn(y[0], y[1]);
    __half2 p1 = __floats2half2_rn(y[2], y[3]);
    __half2 p2 = __floats2half2_rn(y[4], y[5]);
    __half2 p3 = __floats2half2_rn(y[6], y[7]);
    uint4 v;
    v.x = *(u32*)&p0; v.y = *(u32*)&p1; v.z = *(u32*)&p2; v.w = *(u32*)&p3;
    return v;
}

// ---------------- fused prep + proc0: inputs -> x (fp32), y (fp16-packed)
__global__ __launch_bounds__(256) void prep_proc_kernel(
    const float* __restrict__ in, float* __restrict__ x, uint4* __restrict__ y,
    const float* pW0, const float* pb0, const float* pW1, const float* pb1,
    const float* pW2, const float* pb2,
    const float* cW0, const float* cb0, const float* cW1, const float* cb1,
    const float* cW2, const float* cb2, int N)
{
    __shared__ float P0[80],  Pb0[16], P1[512], Pb1[32], P2[256], Pb2[8];
    __shared__ float C0[128], Cb0[16], C1[512], Cb1[32], C2[256], Cb2[8];
    ldw(P0, pW0, 80);  ldw(Pb0, pb0, 16); ldw(P1, pW1, 512); ldw(Pb1, pb1, 32);
    ldw(P2, pW2, 256); ldw(Pb2, pb2, 8);
    ldw(C0, cW0, 128); ldw(Cb0, cb0, 16); ldw(C1, cW1, 512); ldw(Cb1, cb1, 32);
    ldw(C2, cW2, 256); ldw(Cb2, cb2, 8);
    __syncthreads();
    int i = blockIdx.x * 256 + threadIdx.x;
    if (i >= N) return;
    float xin[5];
#pragma unroll
    for (int k = 0; k < 5; ++k) xin[k] = in[(size_t)i * 5 + k];
    float xv[8];
    mlp3<5>(xin, xv, P0, Pb0, P1, Pb1, P2, Pb2);
    float4* xp = (float4*)(x + 8 * (size_t)i);
    xp[0] = make_float4(xv[0], xv[1], xv[2], xv[3]);
    xp[1] = make_float4(xv[4], xv[5], xv[6], xv[7]);
    float yv[8];
    mlp3<8>(xv, yv, C0, Cb0, C1, Cb1, C2, Cb2);
    y[i] = pack_h8(yv);
}

// ---------------- fused agg(sum CHUNKS partials) + masked residual + next proc
template <bool DO_PROC, int CHUNKS>
__global__ __launch_bounds__(256) void aggproc_kernel(
    const uint4* __restrict__ acc, float* __restrict__ x, const float* __restrict__ mask,
    uint4* __restrict__ y,
    const float* aW0, const float* ab0, const float* aW1, const float* ab1,
    const float* aW2, const float* ab2,
    const float* cW0, const float* cb0, const float* cW1, const float* cb1,
    const float* cW2, const float* cb2, int N)
{
    __shared__ float A0[128], Ab0[16], A1[512], Ab1[32], A2[256], Ab2[8];
    __shared__ float C0[128], Cb0[16], C1[512], Cb1[32], C2[256], Cb2[8];
    ldw(A0, aW0, 128); ldw(Ab0, ab0, 16); ldw(A1, aW1, 512); ldw(Ab1, ab1, 32);
    ldw(A2, aW2, 256); ldw(Ab2, ab2, 8);
    if (DO_PROC) {
        ldw(C0, cW0, 128); ldw(Cb0, cb0, 16); ldw(C1, cW1, 512); ldw(Cb1, cb1, 32);
        ldw(C2, cW2, 256); ldw(Cb2, cb2, 8);
    }
    __syncthreads();
    int i = blockIdx.x * 256 + threadIdx.x;
    if (i >= N) return;
    float ain[8] = {0.f, 0.f, 0.f, 0.f, 0.f, 0.f, 0.f, 0.f};
#pragma unroll
    for (int c = 0; c < CHUNKS; ++c) {
        uint4 v = acc[(size_t)c * N + i];
        float2 f0 = __half22float2(*(__half2*)&v.x);
        float2 f1 = __half22float2(*(__half2*)&v.y);
        float2 f2 = __half22float2(*(__half2*)&v.z);
        float2 f3 = __half22float2(*(__half2*)&v.w);
        ain[0] += f0.x; ain[1] += f0.y; ain[2] += f1.x; ain[3] += f1.y;
        ain[4] += f2.x; ain[5] += f2.y; ain[6] += f3.x; ain[7] += f3.y;
    }
    float ya[8];
    mlp3<8>(ain, ya, A0, Ab0, A1, Ab1, A2, Ab2);
    float m = mask[i];
    float4* xp = (float4*)(x + 8 * (size_t)i);
    float4 x0 = xp[0], x1 = xp[1];
    float xn[8] = {x0.x + ya[0] * m, x0.y + ya[1] * m, x0.z + ya[2] * m, x0.w + ya[3] * m,
                   x1.x + ya[4] * m, x1.y + ya[5] * m, x1.z + ya[6] * m, x1.w + ya[7] * m};
    xp[0] = make_float4(xn[0], xn[1], xn[2], xn[3]);
    xp[1] = make_float4(xn[4], xn[5], xn[6], xn[7]);
    if (DO_PROC) {
        float yv[8];
        mlp3<8>(xn, yv, C0, Cb0, C1, Cb1, C2, Cb2);
        y[i] = pack_h8(yv);
    }
}

// ---------------- mask bitmaps for all depths
__global__ __launch_bounds__(256) void mask_pack_kernel(
    const float* __restrict__ masks, u64* __restrict__ bitmaps, int N, int D, int BITW)
{
    int i = blockIdx.x * 256 + threadIdx.x;
    int lane = threadIdx.x & 63;
    for (int d = 0; d < D; ++d) {
        bool b = (i < N) ? (masks[(size_t)d * N + i] != 0.f) : false;
        u64 m = __ballot(b);
        if (lane == 0 && i < N) bitmaps[(size_t)d * BITW + (i >> 6)] = m;
    }
}

// ---------------- single-pass staged binning into (bucket,chunk) cells:
// fixed (cell,block) sub-regions, LDS staging, coalesced drain, no global atomics.
// blockIdx.y = depth (batched mode) or 0 (per-depth mode with pre-offset pointers).
template <int CHUNKS>
__global__ __launch_bounds__(256) void place_kernel(
    const int* __restrict__ adj_src, const int* __restrict__ adj_dst,
    const u64* __restrict__ bitmaps,
    u32* __restrict__ ebuf_all,      // per depth: [NB*CHUNKS * NBLK * SUBC]
    int* __restrict__ cnt_all,       // per depth: [NB*CHUNKS * NBLK]
    int E, int NB, int shift, int BITW)
{
    constexpr int CAPC = Cfg<CHUNKS>::CAPC;
    constexpr int SUBC = Cfg<CHUNKS>::SUBC;
    const int dep = blockIdx.y;
    const int* src = adj_src + (size_t)dep * E;
    const int* dst = adj_dst + (size_t)dep * E;
    const u64* bitmap = bitmaps + (size_t)dep * BITW;
    u32* ebuf = ebuf_all + (size_t)dep * ((size_t)NB * CHUNKS * NBLK * SUBC);
    int* cnt_g = cnt_all + (size_t)dep * ((size_t)NB * CHUNKS * NBLK);

    __shared__ int lcnt[MAXNB * CHUNKS];
    __shared__ u32 stage[MAXNB * CHUNKS * CAPC];
    const int cells = NB * CHUNKS;
    for (int t = threadIdx.x; t < cells; t += 256) lcnt[t] = 0;
    __syncthreads();

    const int blk = blockIdx.x;
    const int E4 = E >> 2;
    const int CH4 = (E4 + NBLK - 1) / NBLK;
    const int base4 = blk * CH4;
    const int lim4 = min(base4 + CH4, E4);
    const int4* src4 = (const int4*)src;
    const int4* dst4 = (const int4*)dst;

#define PLACE(dv, sv) { int _d = (dv); \
    if ((bitmap[_d >> 6] >> (_d & 63)) & 1ull) { \
        int _cell = (_d >> BKT_BITS) * CHUNKS + ((u32)(sv) >> shift); \
        int _slot = atomicAdd(&lcnt[_cell], 1); \
        u32 _w = ((u32)(sv) << BKT_BITS) | (u32)(_d & (BKT_SIZE - 1)); \
        if (_slot < CAPC) stage[_cell * CAPC + _slot] = _w; \
        else if (_slot < SUBC) ebuf[((size_t)_cell * NBLK + blk) * SUBC + _slot] = _w; \
    } }

    for (int i4 = base4 + threadIdx.x; i4 < lim4; i4 += 256) {
        int4 dv = dst4[i4];
        int4 sv = src4[i4];
        PLACE(dv.x, sv.x) PLACE(dv.y, sv.y) PLACE(dv.z, sv.z) PLACE(dv.w, sv.w)
    }
    if (blk == NBLK - 1)
        for (int e = (E4 << 2) + threadIdx.x; e < E; e += 256) { PLACE(dst[e], src[e]) }
#undef PLACE

    __syncthreads();
    // drain: pack several cells per wave iteration; contiguous store per cell
    constexpr int SLOTW = (CAPC <= 8) ? 8 : (CAPC <= 16) ? 16 : 32;
    constexpr int CPW = 64 / SLOTW;   // cells per wave per iteration
    int wave = threadIdx.x >> 6, lane = threadIdx.x & 63;
    int cslot = lane % SLOTW, coff = lane / SLOTW;
    for (int c0 = wave * CPW; c0 < cells; c0 += 4 * CPW) {
        int cell = c0 + coff;
        if (cell < cells) {
            int n = lcnt[cell];
            int ns = min(n, CAPC);
            size_t gb = ((size_t)cell * NBLK + blk) * SUBC;
            if (cslot < ns) ebuf[gb + cslot] = stage[cell * CAPC + cslot];
            if (cslot == 0) cnt_g[cell * NBLK + blk] = min(n, SUBC);
        }
    }
}

// packed-fp16 LDS accumulate: 4 ds_pk_add_f16 per entry, no converts.
// sacc layout: node dl -> 4 half2 slots at stride 5 (bank spread).
__device__ __forceinline__ void accum4(__half2* __restrict__ sacc, u32 w, uint4 v)
{
    int dl = (int)(w & (BKT_SIZE - 1));
    __half2* a = sacc + dl * 5;
    unsafeAtomicAdd(a + 0, *(__half2*)&v.x);
    unsafeAtomicAdd(a + 1, *(__half2*)&v.y);
    unsafeAtomicAdd(a + 2, *(__half2*)&v.z);
    unsafeAtomicAdd(a + 3, *(__half2*)&v.w);
}

// ---------------- per-(bucket,chunk) reduce, thread-per-sub-list, XCD-pinned chunks:
// blockIdx%8 -> XCD (measured round-robin); mapping keeps one src-chunk per XCD so
// each XCD's L2 caches a 2MB slice of y. Writes packed-fp16 partial acc[chunk].
template <int CHUNKS>
__global__ __launch_bounds__(256) void reduce_kernel(
    const uint4* __restrict__ y, const u32* __restrict__ ebuf, const int* __restrict__ cnt_g,
    uint4* __restrict__ acc, int N, int NB)
{
    constexpr int SUBC = Cfg<CHUNKS>::SUBC;
    int i = blockIdx.x, bucket, chunk;
    if (CHUNKS == 4)      { bucket = (i >> 3) * 2 + (i & 1); chunk = (i >> 1) & 3; }
    else if (CHUNKS == 2) { bucket = (i >> 3) * 4 + (i & 3); chunk = (i >> 2) & 1; }
    else                  { bucket = i; chunk = 0; }
    if (bucket >= NB) return;   // uniform across block

    __shared__ __half2 sacc[BKT_SIZE * 5];   // 20 KB; stride 5 spreads banks
    for (int t = threadIdx.x; t < BKT_SIZE * 5; t += 256) ((u32*)sacc)[t] = 0u;
    __syncthreads();

    int cell = bucket * CHUNKS + chunk;
    int sb = cell * NBLK + threadIdx.x;
    int n = cnt_g[sb];
    const u32* r = ebuf + (size_t)sb * SUBC;

    int k = 0;
    for (; k + 3 < n; k += 4) {
        u32 w0 = r[k], w1 = r[k + 1], w2 = r[k + 2], w3 = r[k + 3];
        uint4 v0 = y[w0 >> BKT_BITS];
        uint4 v1 = y[w1 >> BKT_BITS];
        uint4 v2 = y[w2 >> BKT_BITS];
        uint4 v3 = y[w3 >> BKT_BITS];
        accum4(sacc, w0, v0);
        accum4(sacc, w1, v1);
        accum4(sacc, w2, v2);
        accum4(sacc, w3, v3);
    }
    for (; k < n; ++k) {
        u32 w = r[k];
        uint4 v = y[w >> BKT_BITS];
        accum4(sacc, w, v);
    }

    __syncthreads();
    int node0 = bucket << BKT_BITS;
    uint4* accc = acc + (size_t)chunk * N;
    for (int t = threadIdx.x; t < BKT_SIZE; t += 256) {
        int idx = node0 + t;
        if (idx < N) {
            __half2* a = sacc + t * 5;
            uint4 o;
            o.x = *(u32*)(a + 0); o.y = *(u32*)(a + 1);
            o.z = *(u32*)(a + 2); o.w = *(u32*)(a + 3);
            accc[idx] = o;
        }
    }
}

// ---------------- last-resort fallback: global pk fp16 atomics, mask-skip
__global__ __launch_bounds__(256) void scatter_kernel(
    const uint4* __restrict__ y, const int* __restrict__ src, const int* __restrict__ dst,
    const float* __restrict__ mask, __half2* __restrict__ acc, int E)
{
    int e = blockIdx.x * blockDim.x + threadIdx.x;
    if (e >= E) return;
    int d = dst[e];
    if (mask[d] == 0.f) return;
    int s = src[e];
    uint4 v = y[s];
    __half2* o = acc + 4 * (size_t)d;
    unsafeAtomicAdd(o + 0, *(__half2*)&v.x);
    unsafeAtomicAdd(o + 1, *(__half2*)&v.y);
    unsafeAtomicAdd(o + 2, *(__half2*)&v.z);
    unsafeAtomicAdd(o + 3, *(__half2*)&v.w);
}

template <int CH>
static void run_fast(hipStream_t stream, bool batch, int N, int E, int D, int NB, int shift,
                     int BITW, int nbN,
                     const int* adj_src, const int* adj_dst, const float* masks,
                     const u64* bitmaps, u32* ebuf, int* cnt_g,
                     uint4* y, uint4* acc, float* x,
                     const float* aW0, const float* ab0, const float* aW1, const float* ab1,
                     const float* aW2, const float* ab2,
                     const float* cW0, const float* cb0, const float* cW1, const float* cb1,
                     const float* cW2, const float* cb2)
{
    constexpr int SUBC = Cfg<CH>::SUBC;
    const size_t EB = (size_t)NB * CH * NBLK * SUBC;
    const size_t CN = (size_t)NB * CH * NBLK;
    const int rgrid = (CH == 4) ? ((NB + 1) / 2) * 8 : (CH == 2) ? ((NB + 3) / 4) * 8 : NB;

    if (batch)   // all depths in one launch: 2 blocks/CU resident (place is occupancy-bound)
        place_kernel<CH><<<dim3(NBLK, D), 256, 0, stream>>>(adj_src, adj_dst, bitmaps,
                                                            ebuf, cnt_g, E, NB, shift, BITW);

    for (int d = 0; d < D; ++d) {
        const float* mask_d = masks + (size_t)d * N;
        if (!batch)
            place_kernel<CH><<<dim3(NBLK, 1), 256, 0, stream>>>(
                adj_src + (size_t)d * E, adj_dst + (size_t)d * E, bitmaps + (size_t)d * BITW,
                ebuf, cnt_g, E, NB, shift, BITW);
        const u32* eb_d = ebuf + (batch ? (size_t)d * EB : 0);
        const int* cg_d = cnt_g + (batch ? (size_t)d * CN : 0);
        reduce_kernel<CH><<<rgrid, 256, 0, stream>>>(y, eb_d, cg_d, acc, N, NB);
        if (d < D - 1)
            aggproc_kernel<true, CH><<<nbN, 256, 0, stream>>>(acc, x, mask_d, y,
                aW0, ab0, aW1, ab1, aW2, ab2, cW0, cb0, cW1, cb1, cW2, cb2, N);
        else
            aggproc_kernel<false, CH><<<nbN, 256, 0, stream>>>(acc, x, mask_d, y,
                aW0, ab0, aW1, ab1, aW2, ab2, cW0, cb0, cW1, cb1, cW2, cb2, N);
    }
}

extern "C" void kernel_launch(void* const* d_in, const int* in_sizes, int n_in,
                              void* d_out, int out_size, void* d_ws, size_t ws_size,
                              hipStream_t stream)
{
    const float* inputs  = (const float*)d_in[0];
    const int*   adj_src = (const int*)d_in[1];
    const int*   adj_dst = (const int*)d_in[2];
    const float* masks   = (const float*)d_in[3];

    const float* pW0 = (const float*)d_in[4];  const float* pb0 = (const float*)d_in[5];
    const float* pW1 = (const float*)d_in[6];  const float* pb1 = (const float*)d_in[7];
    const float* pW2 = (const float*)d_in[8];  const float* pb2 = (const float*)d_in[9];
    const float* cW0 = (const float*)d_in[10]; const float* cb0 = (const float*)d_in[11];
    const float* cW1 = (const float*)d_in[12]; const float* cb1 = (const float*)d_in[13];
    const float* cW2 = (const float*)d_in[14]; const float* cb2 = (const float*)d_in[15];
    const float* aW0 = (const float*)d_in[16]; const float* ab0 = (const float*)d_in[17];
    const float* aW1 = (const float*)d_in[18]; const float* ab1 = (const float*)d_in[19];
    const float* aW2 = (const float*)d_in[20]; const float* ab2 = (const float*)d_in[21];

    const int N = in_sizes[0] / 5;
    const int D = in_sizes[3] / N;
    const int E = in_sizes[1] / D;
    const int NB = (N + BKT_SIZE - 1) >> BKT_BITS;
    const int BITW = (N + 63) >> 6;

    float* x = (float*)d_out;

    // pick largest config that fits ws: prefer depth-batched place, then larger CH
    auto layout_bytes = [&](int ch, bool batch) -> size_t {
        int subc = (ch == 4) ? 24 : (ch == 2) ? 32 : 64;
        int nd = batch ? D : 1;
        size_t s = 0;
        auto al = [&](size_t b) { s = (s + b + 255) & ~(size_t)255; };
        al((size_t)N * 16);                               // y
        al((size_t)ch * N * 16);                          // acc partials
        al((size_t)D * BITW * 8);                         // bitmaps
        al((size_t)nd * NB * ch * NBLK * subc * 4);       // ebuf
        al((size_t)nd * NB * ch * NBLK * 4);              // cnt_g
        return s;
    };
    int CHsel = 0; bool batch = false;
    if (NB <= MAXNB) {
        struct Opt { int ch; bool b; };
        const Opt opts[6] = {{4,true},{2,true},{1,true},{4,false},{2,false},{1,false}};
        for (int k = 0; k < 6; ++k)
            if (layout_bytes(opts[k].ch, opts[k].b) <= ws_size) { CHsel = opts[k].ch; batch = opts[k].b; break; }
    }
    bool fast = CHsel > 0;
    int subc = (CHsel == 4) ? 24 : (CHsel == 2) ? 32 : 64;
    int nd = batch ? D : 1;

    char* w = (char*)d_ws;
    size_t off = 0;
    auto take = [&](size_t bytes) { char* p = w + off; off = (off + bytes + 255) & ~(size_t)255; return p; };
    uint4* y   = (uint4*)take((size_t)N * 16);
    uint4* acc = (uint4*)take((size_t)(fast ? CHsel : 1) * N * 16);
    u64* bitmaps = (u64*)take((size_t)D * BITW * 8);
    u32* ebuf  = fast ? (u32*)take((size_t)nd * NB * CHsel * NBLK * subc * 4) : nullptr;
    int* cnt_g = fast ? (int*)take((size_t)nd * NB * CHsel * NBLK * 4) : nullptr;

    int shift = 0;
    if (fast) { while ((u32)(N - 1) >> shift >= (u32)CHsel) shift++; }

    const int BLK = 256;
    const int nbN = (N + BLK - 1) / BLK;
    const int nbE = (E + BLK - 1) / BLK;

    if (fast)
        mask_pack_kernel<<<nbN, BLK, 0, stream>>>(masks, bitmaps, N, D, BITW);

    // prep + proc0 -> x, y
    prep_proc_kernel<<<nbN, BLK, 0, stream>>>(inputs, x, y,
                                              pW0, pb0, pW1, pb1, pW2, pb2,
                                              cW0, cb0, cW1, cb1, cW2, cb2, N);

    if (fast) {
        if (CHsel == 4)
            run_fast<4>(stream, batch, N, E, D, NB, shift, BITW, nbN, adj_src, adj_dst, masks,
                        bitmaps, ebuf, cnt_g, y, acc, x,
                        aW0, ab0, aW1, ab1, aW2, ab2, cW0, cb0, cW1, cb1, cW2, cb2);
        else if (CHsel == 2)
            run_fast<2>(stream, batch, N, E, D, NB, shift, BITW, nbN, adj_src, adj_dst, masks,
                        bitmaps, ebuf, cnt_g, y, acc, x,
                        aW0, ab0, aW1, ab1, aW2, ab2, cW0, cb0, cW1, cb1, cW2, cb2);
        else
            run_fast<1>(stream, batch, N, E, D, NB, shift, BITW, nbN, adj_src, adj_dst, masks,
                        bitmaps, ebuf, cnt_g, y, acc, x,
                        aW0, ab0, aW1, ab1, aW2, ab2, cW0, cb0, cW1, cb1, cW2, cb2);
    } else {
        for (int d = 0; d < D; ++d) {
            const float* mask_d = masks + (size_t)d * N;
            const int* src_d = adj_src + (size_t)d * E;
            const int* dst_d = adj_dst + (size_t)d * E;
            bool last = (d == D - 1);
            hipMemsetAsync(acc, 0, (size_t)N * 16, stream);
            scatter_kernel<<<nbE, BLK, 0, stream>>>(y, src_d, dst_d, mask_d, (__half2*)acc, E);
            if (!last)
                aggproc_kernel<true, 1><<<nbN, BLK, 0, stream>>>(acc, x, mask_d, y,
                    aW0, ab0, aW1, ab1, aW2, ab2, cW0, cb0, cW1, cb1, cW2, cb2, N);
            else
                aggproc_kernel<false, 1><<<nbN, BLK, 0, stream>>>(acc, x, mask_d, y,
                    aW0, ab0, aW1, ab1, aW2, ab2, cW0, cb0, cW1, cb1, cW2, cb2, N);
        }
    }
}